// Round 7
// baseline (23.979 us; speedup 1.0000x reference)
//
#include <hip/hip_runtime.h>

// R=16, E=4096, N=262144.
// loss = -sum_i sigmoid(lab_i ? x_i : -x_i) / ((1+neg)*N),
// x_i = pv[rel_i*E*E + e1_i*E + e2_i], neg = #(labels==0).
//
// Single compute kernel + one 2 KB memset node (zeroes the counters every
// graph replay, making last-block detection exact — the init-free mod trick
// of round 6 was racy because the counter's starting residue is unknown).
//
// Atomic-contention control (round-1 lesson: ~14 ns per same-line RMW,
// arriving in a tight window => serialization): 2-level counter tree.
//   level 1: 8 group counters, 128 B apart (parallel across L2s), 32 RMWs each
//   level 2: 1 final counter, 8 RMWs total
// Ordering: release-store partial -> acq_rel RMW(level1) -> acq_rel
// RMW(level2) -> finalizer threads each acquire-load final counter ->
// relaxed slot loads. Release-sequence transitivity => all partials visible.
//
// ws layout (bytes):
//   [0,1024)    8 group counters (uint at byte g*128)
//   [1024,1028) final counter
//   [2048,3072) ws_sum[256] float
//   [3072,4096) ws_neg[256] int
// memset covers [0,2048).

#define NBLK 256
#define TPB  256
#define NGRP 8
#define GRP_SZ (NBLK / NGRP)   // 32

__global__ __launch_bounds__(256) void loss_fused_kernel(
        const float* __restrict__ pv,
        const int* __restrict__ rel_idx,
        const int* __restrict__ e1_idx,
        const int* __restrict__ e2_idx,
        const int* __restrict__ labels,
        float* __restrict__ out,
        unsigned* __restrict__ cnt,     // d_ws base (counters)
        float* __restrict__ ws_sum,     // d_ws + 2048
        int*   __restrict__ ws_neg,     // d_ws + 3072
        int n) {
    int t = blockIdx.x * TPB + threadIdx.x;  // 0..65535, 4 triplets each

    // Coalesced int4 loads of 4 consecutive indices per array.
    int4 r4 = reinterpret_cast<const int4*>(rel_idx)[t];
    int4 a4 = reinterpret_cast<const int4*>(e1_idx)[t];
    int4 b4 = reinterpret_cast<const int4*>(e2_idx)[t];
    int4 L4 = reinterpret_cast<const int4*>(labels)[t];

    const int* rp = &r4.x; const int* ap = &a4.x;
    const int* bp = &b4.x; const int* Lp = &L4.x;
    float x[4];
    #pragma unroll
    for (int k = 0; k < 4; ++k) {
        size_t idx = ((((size_t)rp[k] << 12) | (size_t)ap[k]) << 12) | (size_t)bp[k];
        x[k] = pv[idx];   // 4 independent random gathers in flight
    }

    float term = 0.0f;
    int negc = 0;
    #pragma unroll
    for (int k = 0; k < 4; ++k) {
        float sx = Lp[k] ? -x[k] : x[k];
        term += 1.0f / (1.0f + expf(sx));   // sigmoid(L ? x : -x)
        negc += (Lp[k] == 0) ? 1 : 0;
    }

    // Wave-64 reduction.
    #pragma unroll
    for (int off = 32; off > 0; off >>= 1) {
        term += __shfl_down(term, off, 64);
        negc += __shfl_down(negc, off, 64);
    }

    __shared__ float sterm[4];
    __shared__ int   sneg[4];
    __shared__ int   s_last;
    int lane = threadIdx.x & 63;
    int wid  = threadIdx.x >> 6;
    if (lane == 0) { sterm[wid] = term; sneg[wid] = negc; }
    __syncthreads();

    if (threadIdx.x == 0) {
        float bt = sterm[0] + sterm[1] + sterm[2] + sterm[3];
        int   bc = sneg[0] + sneg[1] + sneg[2] + sneg[3];
        __hip_atomic_store(&ws_sum[blockIdx.x], bt,
                           __ATOMIC_RELEASE, __HIP_MEMORY_SCOPE_AGENT);
        __hip_atomic_store(&ws_neg[blockIdx.x], bc,
                           __ATOMIC_RELEASE, __HIP_MEMORY_SCOPE_AGENT);
        s_last = 0;
        int g = blockIdx.x & (NGRP - 1);
        unsigned o1 = __hip_atomic_fetch_add(&cnt[g * 32], 1u,
                           __ATOMIC_ACQ_REL, __HIP_MEMORY_SCOPE_AGENT);
        if (o1 == GRP_SZ - 1) {              // last in group
            unsigned o2 = __hip_atomic_fetch_add(&cnt[256], 1u,
                               __ATOMIC_ACQ_REL, __HIP_MEMORY_SCOPE_AGENT);
            if (o2 == NGRP - 1) s_last = 1;  // last group -> true last block
        }
    }
    __syncthreads();

    if (s_last) {
        // Per-thread acquire on the final counter: synchronizes-with the
        // whole release-RMW chain => all 256 partial stores are visible.
        (void)__hip_atomic_load(&cnt[256], __ATOMIC_ACQUIRE,
                                __HIP_MEMORY_SCOPE_AGENT);
        int i = threadIdx.x;  // 256 threads, 256 slots: fixed order
        float ft = __hip_atomic_load(&ws_sum[i], __ATOMIC_RELAXED,
                                     __HIP_MEMORY_SCOPE_AGENT);
        int   fc = __hip_atomic_load(&ws_neg[i], __ATOMIC_RELAXED,
                                     __HIP_MEMORY_SCOPE_AGENT);
        #pragma unroll
        for (int off = 32; off > 0; off >>= 1) {
            ft += __shfl_down(ft, off, 64);
            fc += __shfl_down(fc, off, 64);
        }
        __syncthreads();   // safe: s_last is block-uniform; reuse sterm/sneg
        if (lane == 0) { sterm[wid] = ft; sneg[wid] = fc; }
        __syncthreads();
        if (threadIdx.x == 0) {
            double total = (double)(sterm[0] + sterm[1] + sterm[2] + sterm[3]);
            double neg   = (double)(sneg[0] + sneg[1] + sneg[2] + sneg[3]);
            out[0] = (float)(-total / ((1.0 + neg) * (double)n));
        }
    }
}

extern "C" void kernel_launch(void* const* d_in, const int* in_sizes, int n_in,
                              void* d_out, int out_size, void* d_ws, size_t ws_size,
                              hipStream_t stream) {
    const float* pv      = (const float*)d_in[0];
    const int*   rel_idx = (const int*)d_in[1];
    const int*   e1_idx  = (const int*)d_in[2];
    const int*   e2_idx  = (const int*)d_in[3];
    const int*   labels  = (const int*)d_in[4];
    float* out = (float*)d_out;

    unsigned* cnt    = (unsigned*)d_ws;
    float*    ws_sum = (float*)((char*)d_ws + 2048);
    int*      ws_neg = (int*)((char*)d_ws + 3072);

    int n = in_sizes[1];  // N = 262144 = NBLK*TPB*4

    // Capturable async memset node: zero the counters before every replay.
    hipMemsetAsync(d_ws, 0, 2048, stream);
    loss_fused_kernel<<<NBLK, TPB, 0, stream>>>(pv, rel_idx, e1_idx, e2_idx,
                                                labels, out, cnt, ws_sum,
                                                ws_neg, n);
}

// Round 8
// 15.886 us; speedup vs baseline: 1.5095x; 1.5095x over previous
//
#include <hip/hip_runtime.h>

// R=16, E=4096, N=262144.
// loss = -sum_i sigmoid(lab_i ? x_i : -x_i) / ((1+neg)*N),
// x_i = pv[rel_i*E*E + e1_i*E + e2_i], neg = #(labels==0).
//
// Single fused kernel + 2 KB memset node (zeroed counters each replay).
// Round-7 lesson: agent-scope RELEASE/ACQ_REL atomics emit per-op L2
// writeback/invalidate on gfx950 (non-coherent per-XCD L2s) -> +12 us.
// This version uses ONLY relaxed device-scope atomic RMWs, which execute
// coherently at the LLC with no cache maintenance:
//   - partials:  atomicExch into per-block slots (single writer, exact value)
//   - ordering:  consume exch results in a free asm() with "memory" clobber
//                -> compiler emits s_waitcnt vmcnt(0) before the counter RMW
//                (slot writes complete at LLC before counter increments)
//   - counters:  2-level tree (8 group counters 128B apart x32 incs, then 1
//                final x8 incs) -> exact last-block detection, low contention
//   - finalizer: atomicOr(slot,0) coherent reads, fixed-order tree reduce
//                -> bitwise deterministic output.
//
// ws layout (bytes): [0,1024) 8 group counters (uint at g*128);
//                    [1024,1028) final counter; memset covers [0,2048)
//                    [2048,3072) slot_sum[256] float
//                    [3072,4096) slot_neg[256] int

#define NBLK 256
#define TPB  512   // 8 waves/CU at 1 block/CU: TLP for the random gathers
#define NGRP 8
#define GRP_SZ (NBLK / NGRP)   // 32

__global__ __launch_bounds__(512) void loss_fused_kernel(
        const float* __restrict__ pv,
        const int* __restrict__ rel_idx,
        const int* __restrict__ e1_idx,
        const int* __restrict__ e2_idx,
        const int* __restrict__ labels,
        float* __restrict__ out,
        unsigned* __restrict__ cnt,      // d_ws base
        float* __restrict__ slot_sum,    // d_ws + 2048
        int*   __restrict__ slot_neg,    // d_ws + 3072
        int n) {
    int t = blockIdx.x * TPB + threadIdx.x;  // 0..131071, 2 triplets each

    int2 r2 = reinterpret_cast<const int2*>(rel_idx)[t];
    int2 a2 = reinterpret_cast<const int2*>(e1_idx)[t];
    int2 b2 = reinterpret_cast<const int2*>(e2_idx)[t];
    int2 L2 = reinterpret_cast<const int2*>(labels)[t];

    size_t i0 = ((((size_t)r2.x << 12) | (size_t)a2.x) << 12) | (size_t)b2.x;
    size_t i1 = ((((size_t)r2.y << 12) | (size_t)a2.y) << 12) | (size_t)b2.y;
    float x0 = pv[i0];            // 2 independent random gathers in flight
    float x1 = pv[i1];

    float s0 = L2.x ? -x0 : x0;   // sigmoid(L ? x : -x) = L?sig(x):1-sig(x)
    float s1 = L2.y ? -x1 : x1;
    float term = 1.0f / (1.0f + expf(s0)) + 1.0f / (1.0f + expf(s1));
    int negc = (L2.x == 0) + (L2.y == 0);

    #pragma unroll
    for (int off = 32; off > 0; off >>= 1) {
        term += __shfl_down(term, off, 64);
        negc += __shfl_down(negc, off, 64);
    }

    __shared__ float sterm[8];
    __shared__ int   sneg[8];
    __shared__ int   s_last;
    int lane = threadIdx.x & 63;
    int wid  = threadIdx.x >> 6;
    if (lane == 0) { sterm[wid] = term; sneg[wid] = negc; }
    __syncthreads();

    if (threadIdx.x == 0) {
        float bt = 0.0f; int bc = 0;
        #pragma unroll
        for (int w = 0; w < 8; ++w) { bt += sterm[w]; bc += sneg[w]; }

        // Publish partials via relaxed device-scope RMWs (coherent at LLC,
        // no cache flush). Consume results -> vmcnt(0) before counter RMW.
        float r0 = atomicExch(&slot_sum[blockIdx.x], bt);
        int   r1 = atomicExch(&slot_neg[blockIdx.x], bc);
        asm volatile("" : : "v"(r0), "v"(r1) : "memory");

        s_last = 0;
        unsigned o1 = atomicAdd(&cnt[(blockIdx.x & (NGRP - 1)) * 32], 1u);
        if (o1 == GRP_SZ - 1) {                 // last block in my group
            unsigned o2 = atomicAdd(&cnt[256], 1u);
            if (o2 == NGRP - 1) s_last = 1;     // true last block overall
        }
    }
    __syncthreads();

    if (s_last) {
        // All 256 slot-exchanges completed at LLC before their counter
        // increments, which all precede ours -> coherent RMW reads see them.
        int i = threadIdx.x;
        float ft = 0.0f; int fc = 0;
        if (i < NBLK) {
            unsigned ub = atomicOr(reinterpret_cast<unsigned*>(&slot_sum[i]), 0u);
            ft = __uint_as_float(ub);
            fc = (int)atomicOr(reinterpret_cast<unsigned*>(&slot_neg[i]), 0u);
        }
        #pragma unroll
        for (int off = 32; off > 0; off >>= 1) {
            ft += __shfl_down(ft, off, 64);
            fc += __shfl_down(fc, off, 64);
        }
        __syncthreads();          // block-uniform branch; safe LDS reuse
        if (lane == 0) { sterm[wid] = ft; sneg[wid] = fc; }
        __syncthreads();
        if (threadIdx.x == 0) {
            float tt = 0.0f; int tc = 0;
            #pragma unroll
            for (int w = 0; w < 8; ++w) { tt += sterm[w]; tc += sneg[w]; }
            double total = (double)tt;
            double neg   = (double)tc;
            out[0] = (float)(-total / ((1.0 + neg) * (double)n));
        }
    }
}

extern "C" void kernel_launch(void* const* d_in, const int* in_sizes, int n_in,
                              void* d_out, int out_size, void* d_ws, size_t ws_size,
                              hipStream_t stream) {
    const float* pv      = (const float*)d_in[0];
    const int*   rel_idx = (const int*)d_in[1];
    const int*   e1_idx  = (const int*)d_in[2];
    const int*   e2_idx  = (const int*)d_in[3];
    const int*   labels  = (const int*)d_in[4];
    float* out = (float*)d_out;

    unsigned* cnt      = (unsigned*)d_ws;
    float*    slot_sum = (float*)((char*)d_ws + 2048);
    int*      slot_neg = (int*)((char*)d_ws + 3072);

    int n = in_sizes[1];  // N = 262144 = NBLK*TPB*2

    hipMemsetAsync(d_ws, 0, 2048, stream);   // zero counters (capturable)
    loss_fused_kernel<<<NBLK, TPB, 0, stream>>>(pv, rel_idx, e1_idx, e2_idx,
                                                labels, out, cnt, slot_sum,
                                                slot_neg, n);
}

// Round 9
// 12.075 us; speedup vs baseline: 1.9859x; 1.3156x over previous
//
#include <hip/hip_runtime.h>

// R=16, E=4096, N=262144.
// loss = -sum_i sigmoid(lab_i ? x_i : -x_i) / ((1+neg)*N),
// x_i = pv[rel_i*E*E + e1_i*E + e2_i], neg = #(labels==0).
//
// Proven 2-kernel structure (R5: 11.6 us). Change vs R5: occupancy of the
// gather kernel 4 -> 8 waves/CU (512 blocks x 128 threads, ILP-4 kept):
// doubles outstanding random gathers per CU for the latency-bound phase.
//  K1: 512 blocks x 128 threads, 4 triplets/thread -> 512 partials.
//  K2: 1 block x 256 threads reduces 512 partials, writes loss.
// No atomics, no ws init needed, bitwise-deterministic output.

#define NBLK 512
#define TPB  128

__global__ __launch_bounds__(128) void loss_partial_kernel(
        const float* __restrict__ pv,
        const int* __restrict__ rel_idx,
        const int* __restrict__ e1_idx,
        const int* __restrict__ e2_idx,
        const int* __restrict__ labels,
        float* __restrict__ ws_sum,   // [NBLK]
        int*   __restrict__ ws_neg) { // [NBLK]
    int t = blockIdx.x * TPB + threadIdx.x;  // 0..65535

    // Coalesced int4 loads of 4 consecutive indices per array.
    int4 r4 = reinterpret_cast<const int4*>(rel_idx)[t];
    int4 a4 = reinterpret_cast<const int4*>(e1_idx)[t];
    int4 b4 = reinterpret_cast<const int4*>(e2_idx)[t];
    int4 L4 = reinterpret_cast<const int4*>(labels)[t];

    const int* rp = &r4.x; const int* ap = &a4.x;
    const int* bp = &b4.x; const int* Lp = &L4.x;
    float x[4];
    #pragma unroll
    for (int k = 0; k < 4; ++k) {
        size_t idx = ((((size_t)rp[k] << 12) | (size_t)ap[k]) << 12) | (size_t)bp[k];
        x[k] = pv[idx];   // 4 independent random gathers in flight
    }

    float term = 0.0f;
    int negc = 0;
    #pragma unroll
    for (int k = 0; k < 4; ++k) {
        float sx = Lp[k] ? -x[k] : x[k];
        term += 1.0f / (1.0f + expf(sx));   // sigmoid(L ? x : -x)
        negc += (Lp[k] == 0) ? 1 : 0;
    }

    // Wave-64 reduction (2 waves per block).
    #pragma unroll
    for (int off = 32; off > 0; off >>= 1) {
        term += __shfl_down(term, off, 64);
        negc += __shfl_down(negc, off, 64);
    }

    __shared__ float sterm[2];
    __shared__ int   sneg[2];
    int lane = threadIdx.x & 63;
    int wid  = threadIdx.x >> 6;
    if (lane == 0) { sterm[wid] = term; sneg[wid] = negc; }
    __syncthreads();

    if (threadIdx.x == 0) {
        ws_sum[blockIdx.x] = sterm[0] + sterm[1];
        ws_neg[blockIdx.x] = sneg[0] + sneg[1];
    }
}

__global__ __launch_bounds__(256) void loss_final_kernel(
        const float* __restrict__ ws_sum,
        const int*   __restrict__ ws_neg,
        float* __restrict__ out, int n) {
    int i = threadIdx.x;
    float term = ws_sum[i] + ws_sum[i + 256];
    int   negc = ws_neg[i] + ws_neg[i + 256];
    #pragma unroll
    for (int off = 32; off > 0; off >>= 1) {
        term += __shfl_down(term, off, 64);
        negc += __shfl_down(negc, off, 64);
    }
    __shared__ float sterm[4];
    __shared__ int   sneg[4];
    int lane = threadIdx.x & 63;
    int wid  = threadIdx.x >> 6;
    if (lane == 0) { sterm[wid] = term; sneg[wid] = negc; }
    __syncthreads();
    if (threadIdx.x == 0) {
        double total = (double)(sterm[0] + sterm[1] + sterm[2] + sterm[3]);
        double neg   = (double)(sneg[0] + sneg[1] + sneg[2] + sneg[3]);
        out[0] = (float)(-total / ((1.0 + neg) * (double)n));
    }
}

extern "C" void kernel_launch(void* const* d_in, const int* in_sizes, int n_in,
                              void* d_out, int out_size, void* d_ws, size_t ws_size,
                              hipStream_t stream) {
    const float* pv      = (const float*)d_in[0];
    const int*   rel_idx = (const int*)d_in[1];
    const int*   e1_idx  = (const int*)d_in[2];
    const int*   e2_idx  = (const int*)d_in[3];
    const int*   labels  = (const int*)d_in[4];
    float* out = (float*)d_out;

    float* ws_sum = (float*)d_ws;
    int*   ws_neg = (int*)((char*)d_ws + NBLK * sizeof(float));

    int n = in_sizes[1];  // N = 262144 = NBLK*TPB*4

    loss_partial_kernel<<<NBLK, TPB, 0, stream>>>(pv, rel_idx, e1_idx, e2_idx,
                                                  labels, ws_sum, ws_neg);
    loss_final_kernel<<<1, 256, 0, stream>>>(ws_sum, ws_neg, out, n);
}